// Round 5
// baseline (221.378 us; speedup 1.0000x reference)
//
#include <hip/hip_runtime.h>
#include <stdint.h>

#define NTOK 16384
#define CDIM 1024
#define DHEAD 256

typedef short s16x8 __attribute__((ext_vector_type(8)));
typedef unsigned short u16x8 __attribute__((ext_vector_type(8)));
typedef _Float16 h16x8 __attribute__((ext_vector_type(8)));
typedef float f32x4 __attribute__((ext_vector_type(4)));

static __device__ __forceinline__ unsigned short f2bf(float f) {
    union { float f; unsigned u; } x; x.f = f;
    unsigned r = (x.u + 0x7fffu + ((x.u >> 16) & 1u)) >> 16;
    return (unsigned short)r;
}
static __device__ __forceinline__ unsigned short f2h(float f) {
    _Float16 h = (_Float16)f;
    return __builtin_bit_cast(unsigned short, h);
}
// Barrier ordering LDS only — global loads stay in flight across it (T4).
static __device__ __forceinline__ void lgkm_barrier() {
    asm volatile("s_waitcnt lgkmcnt(0)" ::: "memory");
    __builtin_amdgcn_s_barrier();
}

// ---------------------------------------------------------------------------
// Kernel 1: partial Gram G[de][e] over an n-chunk + per-channel sums.
// 1024 thr / 16 waves. Register math: acc 64 AGPR + ~110 arch VGPR << 256
// cap at 2 blocks/CU -> NO SPILL (R4's 128-VGPR cap caused scratch traffic).
// Load roles: t<512 loads q, t>=512 loads k (8 f32x4/thread/stage, A/B halves).
// Wave tile 64x64 (de0=(w>>2)*64, e0=(w&3)*64), 2 kk-steps of K=32.
// LDS [ch][64n] bf16 with 16B-slot XOR swizzle (unchanged).
// ---------------------------------------------------------------------------
__global__ __launch_bounds__(1024, 2)
void k_gram(const float* __restrict__ q, const float* __restrict__ k,
            unsigned short* __restrict__ Gpart, float* __restrict__ Spart, int nchunk)
{
    __shared__ __align__(16) unsigned short ls[2 * DHEAD * 64];   // 64 KB
    unsigned short* lq = ls;
    unsigned short* lk = ls + DHEAD * 64;

    const int t     = threadIdx.x;
    const int bh    = blockIdx.x & 7;
    const int chunk = blockIdx.x >> 3;
    const int b     = bh >> 2, h = bh & 3;
    const int rows  = NTOK / nchunk;    // 512 at nchunk=32
    const int S     = rows >> 6;        // 8 stages of 64 rows
    const int n0c   = chunk * rows;

    const int lane = t & 63, w = t >> 6;   // w in 0..15
    const int isK  = t >> 9;               // 0: load q, 1: load k
    const int tl   = t & 511;
    const int ng   = tl & 7;               // n-slot (8 rows each)
    const int ch0  = ((tl >> 3) & 63) * 4; // channel quad
    const int de0  = (w >> 2) * 64;
    const int e0   = (w & 3) * 64;

    const float* src = isK ? k : q;
    unsigned short* dst = isK ? lk : lq;
    const float* row0 = src + ((size_t)b * NTOK + n0c + ng * 8) * CDIM + (size_t)h * DHEAD + ch0;

    f32x4 vA[4], vB[4];
#define GL_A(sidx) do { const size_t o_ = (size_t)(sidx) * 64 * CDIM;                \
        _Pragma("unroll") for (int j_ = 0; j_ < 4; ++j_)                              \
            vA[j_] = *reinterpret_cast<const f32x4*>(row0 + o_ + (size_t)j_ * CDIM);   \
    } while (0)
#define GL_B(sidx) do { const size_t o_ = (size_t)(sidx) * 64 * CDIM + 4 * CDIM;     \
        _Pragma("unroll") for (int j_ = 0; j_ < 4; ++j_)                              \
            vB[j_] = *reinterpret_cast<const f32x4*>(row0 + o_ + (size_t)j_ * CDIM);   \
    } while (0)

    GL_A(0);
    GL_B(0);

    float ssum[4] = {0.f, 0.f, 0.f, 0.f};
    f32x4 acc[4][4];
#pragma unroll
    for (int r = 0; r < 4; ++r)
#pragma unroll
        for (int c = 0; c < 4; ++c) acc[r][c] = (f32x4){0.f, 0.f, 0.f, 0.f};

    for (int s = 0; s < S; ++s) {
        // ---- consume half A (rows ng*8+0..3): lower 8B of the 16B slot ----
#pragma unroll
        for (int c = 0; c < 4; ++c) {
            const int ch = ch0 + c;
            ushort4 p;
            p.x = f2bf(vA[0][c]); p.y = f2bf(vA[1][c]);
            p.z = f2bf(vA[2][c]); p.w = f2bf(vA[3][c]);
            ssum[c] += (vA[0][c] + vA[1][c]) + (vA[2][c] + vA[3][c]);
            *reinterpret_cast<ushort4*>(&dst[ch * 64 + ((ng ^ (ch & 7)) * 8)]) = p;
        }
        if (s + 1 < S) GL_A(s + 1);

        // ---- consume half B (rows ng*8+4..7): upper 8B of the slot ----
#pragma unroll
        for (int c = 0; c < 4; ++c) {
            const int ch = ch0 + c;
            ushort4 p;
            p.x = f2bf(vB[0][c]); p.y = f2bf(vB[1][c]);
            p.z = f2bf(vB[2][c]); p.w = f2bf(vB[3][c]);
            ssum[c] += (vB[0][c] + vB[1][c]) + (vB[2][c] + vB[3][c]);
            *reinterpret_cast<ushort4*>(&dst[ch * 64 + ((ng ^ (ch & 7)) * 8) + 4]) = p;
        }
        if (s + 1 < S) GL_B(s + 1);

        lgkm_barrier();

        // ---- MFMA: 2 k-steps of 32 n ----
#pragma unroll
        for (int kk = 0; kk < 2; ++kk) {
            s16x8 af[4], bfr[4];
#pragma unroll
            for (int r = 0; r < 4; ++r) {
                const int row  = de0 + r * 16 + (lane & 15);
                const int slot = kk * 4 + (lane >> 4);
                af[r] = *reinterpret_cast<const s16x8*>(&lq[row * 64 + ((slot ^ (row & 7)) * 8)]);
            }
#pragma unroll
            for (int c = 0; c < 4; ++c) {
                const int row  = e0 + c * 16 + (lane & 15);
                const int slot = kk * 4 + (lane >> 4);
                bfr[c] = *reinterpret_cast<const s16x8*>(&lk[row * 64 + ((slot ^ (row & 7)) * 8)]);
            }
#pragma unroll
            for (int r = 0; r < 4; ++r)
#pragma unroll
                for (int c = 0; c < 4; ++c)
                    acc[r][c] = __builtin_amdgcn_mfma_f32_16x16x32_bf16(af[r], bfr[c], acc[r][c], 0, 0, 0);
        }
        lgkm_barrier();
    }
#undef GL_A
#undef GL_B

    // ---- per-channel partial sums: reduce across the 8-lane octet ----
#pragma unroll
    for (int off = 1; off < 8; off <<= 1)
#pragma unroll
        for (int c = 0; c < 4; ++c) ssum[c] += __shfl_xor(ssum[c], off);
    if ((lane & 7) == 0) {
        float* sp = Spart + (size_t)(bh * nchunk + chunk) * 512 + isK * 256;
        *reinterpret_cast<float4*>(&sp[ch0]) = make_float4(ssum[0], ssum[1], ssum[2], ssum[3]);
    }

    // ---- Gpart (fp16) via LDS transpose: two 128-row halves, coalesced out ----
    unsigned short* gp = Gpart + (size_t)(bh * nchunk + chunk) * 65536;
#pragma unroll
    for (int half = 0; half < 2; ++half) {
        if ((de0 >> 7) == half) {
#pragma unroll
            for (int r = 0; r < 4; ++r) {
                const int de_b = (de0 & 127) + r * 16 + (lane >> 4) * 4;
#pragma unroll
                for (int c = 0; c < 4; ++c) {
                    const int e = e0 + c * 16 + (lane & 15);
#pragma unroll
                    for (int reg = 0; reg < 4; ++reg)
                        ls[(de_b + reg) * 256 + e] = f2h(acc[r][c][reg]);
                }
            }
        }
        lgkm_barrier();
#pragma unroll
        for (int i = 0; i < 4; ++i) {
            const int idx = i * 1024 + t;
            *reinterpret_cast<u16x8*>(gp + half * 32768 + idx * 8) =
                *reinterpret_cast<const u16x8*>(&ls[idx * 8]);
        }
        lgkm_barrier();
    }
}

// ---------------------------------------------------------------------------
// Kernel 2: fused chunk-reduce + scores + softmax (both branches) + W/beta.
// ---------------------------------------------------------------------------
__global__ __launch_bounds__(256)
void k_scores(const unsigned short* __restrict__ Gpart, const float* __restrict__ Spart,
              const float* __restrict__ wqg, const float* __restrict__ bqg,
              const float* __restrict__ wkg, const float* __restrict__ bkg,
              const float* __restrict__ wvg, const float* __restrict__ bvg,
              const float* __restrict__ wql, const float* __restrict__ bql,
              const float* __restrict__ wkl, const float* __restrict__ bkl,
              const float* __restrict__ wvl, const float* __restrict__ bvl,
              const float* __restrict__ wp,  const float* __restrict__ bp,
              unsigned short* __restrict__ Wm, float* __restrict__ beta, int nchunk)
{
    __shared__ float sSq[256], sSk[256];
    const int t  = threadIdx.x;
    const int bh = blockIdx.x >> 5;
    const int rg = blockIdx.x & 31;
    const int h  = bh & 3;

    float aq = 0.f, ak = 0.f;
    for (int c = 0; c < nchunk; ++c) {
        const float* sp = Spart + (size_t)(bh * nchunk + c) * 512;
        aq += sp[t]; ak += sp[256 + t];
    }
    sSq[t] = aq; sSk[t] = ak;
    __syncthreads();

    const int dl  = t >> 5;
    const int de  = rg * 8 + dl;
    const int e8  = (t & 31) * 8;
    const int cd  = h * DHEAD + de;
    const int ce0 = h * DHEAD + e8;

    float g[8] = {0.f, 0.f, 0.f, 0.f, 0.f, 0.f, 0.f, 0.f};
    const unsigned short* gpb = Gpart + (size_t)bh * nchunk * 65536 + (size_t)de * 256 + e8;
    for (int c = 0; c < nchunk; ++c) {
        h16x8 v = *reinterpret_cast<const h16x8*>(gpb + (size_t)c * 65536);
#pragma unroll
        for (int j = 0; j < 8; ++j) g[j] += (float)v[j];
    }

    const float sqv = sSq[de];
    float skv[8];
#pragma unroll
    for (int j = 0; j < 8; ++j) skv[j] = sSk[e8 + j];

    float wrow[8] = {0.f, 0.f, 0.f, 0.f, 0.f, 0.f, 0.f, 0.f};
    float bacc = 0.f;
    const float scale = 0.03125f;
#pragma unroll
    for (int br = 0; br < 2; ++br) {
        const float* wq = br ? wql : wqg;  const float* bq = br ? bql : bqg;
        const float* wk = br ? wkl : wkg;  const float* bk = br ? bkl : bkg;
        const float* wv = br ? wvl : wvg;  const float* bv = br ? bvl : bvg;
        const float wqv = wq[cd], bqv = bq[cd];

        float s[8], m = -1e30f;
#pragma unroll
        for (int j = 0; j < 8; ++j) {
            const float wkv = wk[ce0 + j], bkv = bk[ce0 + j];
            s[j] = scale * (wqv * wkv * g[j] + wqv * bkv * sqv
                            + bqv * wkv * skv[j] + bqv * bkv * 16384.0f);
            m = fmaxf(m, s[j]);
        }
#pragma unroll
        for (int off = 16; off; off >>= 1) m = fmaxf(m, __shfl_xor(m, off));
        float p[8], sum = 0.f;
#pragma unroll
        for (int j = 0; j < 8; ++j) { p[j] = __expf(s[j] - m); sum += p[j]; }
#pragma unroll
        for (int off = 16; off; off >>= 1) sum += __shfl_xor(sum, off);
        const float inv = 1.f / sum;
#pragma unroll
        for (int j = 0; j < 8; ++j) {
            const float a = p[j] * inv;
            wrow[j] += a * wv[ce0 + j];
            bacc    += a * bv[ce0 + j];
        }
    }
    const float wp2 = 2.f * wp[cd];
    u16x8 pw;
#pragma unroll
    for (int j = 0; j < 8; ++j) pw[j] = f2bf(wp2 * wrow[j]);
    *reinterpret_cast<u16x8*>(Wm + (size_t)bh * 65536 + (size_t)de * 256 + e8) = pw;
#pragma unroll
    for (int off = 16; off; off >>= 1) bacc += __shfl_xor(bacc, off);
    if ((t & 31) == 0) beta[bh * 256 + de] = wp2 * bacc + bp[cd];
}

// ---------------------------------------------------------------------------
// Kernel 3: Out[n][dd] = sum_e W[dd][e]*v[n][ce] + beta[dd].
// 512 thr (8 waves as 4n x 2dd, wave tile 32n x 128dd, acc 64 AGPR) ->
// ~190 regs/wave -> 2 blocks/CU (16 waves) for cross-block latency hiding.
// ---------------------------------------------------------------------------
__global__ __launch_bounds__(512, 2)
void k_out(const float* __restrict__ v, const unsigned short* __restrict__ Wm,
           const float* __restrict__ beta, float* __restrict__ out)
{
    __shared__ __align__(16) unsigned short lv[128 * 256];
    const int t    = threadIdx.x;
    const int bh   = blockIdx.x & 7;
    const int tile = blockIdx.x >> 3;
    const int b    = bh >> 2, h = bh & 3;
    const int n0   = tile * 128;

#pragma unroll
    for (int i = 0; i < 8; ++i) {
        const int sf = i * 512 + t;
        const int n  = sf >> 5, s = sf & 31;
        const float* vp = v + ((size_t)b * NTOK + n0 + n) * CDIM + (size_t)h * DHEAD + s * 8;
        const float4 v0 = *reinterpret_cast<const float4*>(vp);
        const float4 v1 = *reinterpret_cast<const float4*>(vp + 4);
        const int idx = n * 256 + ((s ^ (n & 7)) * 8);
        *reinterpret_cast<ushort4*>(&lv[idx])     = make_ushort4(f2bf(v0.x), f2bf(v0.y), f2bf(v0.z), f2bf(v0.w));
        *reinterpret_cast<ushort4*>(&lv[idx + 4]) = make_ushort4(f2bf(v1.x), f2bf(v1.y), f2bf(v1.z), f2bf(v1.w));
    }
    __syncthreads();

    const int w = t >> 6, lane = t & 63;
    const int nw  = (w >> 1) * 32;     // 4 n-groups of 32
    const int dd0 = (w & 1) * 128;     // 2 dd-groups of 128
    const unsigned short* Wg = Wm + (size_t)bh * 65536;

    f32x4 acc[2][8];
#pragma unroll
    for (int r = 0; r < 2; ++r)
#pragma unroll
        for (int c = 0; c < 8; ++c) acc[r][c] = (f32x4){0.f, 0.f, 0.f, 0.f};

#pragma unroll
    for (int ks = 0; ks < 8; ++ks) {
        const int e0 = ks * 32;
        s16x8 af[2], bfr[8];
#pragma unroll
        for (int r = 0; r < 2; ++r) {
            const int n  = nw + r * 16 + (lane & 15);
            const int sg = (e0 >> 3) + (lane >> 4);
            af[r] = *reinterpret_cast<const s16x8*>(&lv[n * 256 + ((sg ^ (n & 7)) * 8)]);
        }
#pragma unroll
        for (int c = 0; c < 8; ++c) {
            const int dd = dd0 + c * 16 + (lane & 15);
            const int e  = e0 + (lane >> 4) * 8;
            bfr[c] = *reinterpret_cast<const s16x8*>(Wg + (size_t)dd * 256 + e);
        }
#pragma unroll
        for (int r = 0; r < 2; ++r)
#pragma unroll
            for (int c = 0; c < 8; ++c)
                acc[r][c] = __builtin_amdgcn_mfma_f32_16x16x32_bf16(af[r], bfr[c], acc[r][c], 0, 0, 0);
    }

    float betar[8];
#pragma unroll
    for (int c = 0; c < 8; ++c) betar[c] = beta[bh * 256 + dd0 + c * 16 + (lane & 15)];

#pragma unroll
    for (int r = 0; r < 2; ++r)
#pragma unroll
        for (int c = 0; c < 8; ++c) {
            const int dd = dd0 + c * 16 + (lane & 15);
#pragma unroll
            for (int reg = 0; reg < 4; ++reg) {
                const int n = nw + r * 16 + (lane >> 4) * 4 + reg;
                out[((size_t)b * NTOK + n0 + n) * CDIM + (size_t)h * DHEAD + dd] =
                    acc[r][c][reg] + betar[c];
            }
        }
}

// ---------------------------------------------------------------------------
extern "C" void kernel_launch(void* const* d_in, const int* in_sizes, int n_in,
                              void* d_out, int out_size, void* d_ws, size_t ws_size,
                              hipStream_t stream)
{
    const float* q = (const float*)d_in[0];
    const float* k = (const float*)d_in[1];
    const float* v = (const float*)d_in[2];
    const float* wgt[14];
    for (int i = 0; i < 14; ++i) wgt[i] = (const float*)d_in[3 + i];
    float* out = (float*)d_out;

    int nchunk = 32;
    while (nchunk > 1) {
        size_t need = (size_t)8 * nchunk * 65536 * 2   // Gpart fp16
                    + (size_t)8 * nchunk * 512 * 4     // Spart
                    + (size_t)8 * 65536 * 2            // W bf16
                    + (size_t)8 * 256 * 4 + 1024;      // beta + slack
        if (need <= ws_size) break;
        nchunk >>= 1;
    }

    char* p = (char*)d_ws;
    unsigned short* Gpart = (unsigned short*)p; p += (size_t)8 * nchunk * 65536 * 2;
    float* Spart = (float*)p;                   p += (size_t)8 * nchunk * 512 * 4;
    unsigned short* Wm = (unsigned short*)p;    p += (size_t)8 * 65536 * 2;
    float* beta  = (float*)p;

    k_gram<<<dim3(8 * nchunk), dim3(1024), 0, stream>>>(q, k, Gpart, Spart, nchunk);
    k_scores<<<dim3(8 * 32), dim3(256), 0, stream>>>(
        Gpart, Spart,
        wgt[0], wgt[1], wgt[2], wgt[3], wgt[4], wgt[5],
        wgt[6], wgt[7], wgt[8], wgt[9], wgt[10], wgt[11],
        wgt[12], wgt[13], Wm, beta, nchunk);
    k_out<<<dim3(8 * 128), dim3(512), 0, stream>>>(v, Wm, beta, out);
}

// Round 6
// 185.748 us; speedup vs baseline: 1.1918x; 1.1918x over previous
//
#include <hip/hip_runtime.h>
#include <stdint.h>

#define NTOK 16384
#define CDIM 1024
#define DHEAD 256

typedef short s16x8 __attribute__((ext_vector_type(8)));
typedef unsigned short u16x8 __attribute__((ext_vector_type(8)));
typedef _Float16 h16x8 __attribute__((ext_vector_type(8)));
typedef float f32x4 __attribute__((ext_vector_type(4)));

static __device__ __forceinline__ unsigned short f2bf(float f) {
    union { float f; unsigned u; } x; x.f = f;
    unsigned r = (x.u + 0x7fffu + ((x.u >> 16) & 1u)) >> 16;
    return (unsigned short)r;
}
static __device__ __forceinline__ unsigned short f2h(float f) {
    _Float16 h = (_Float16)f;
    return __builtin_bit_cast(unsigned short, h);
}
// Barrier ordering LDS only — global loads stay in flight across it (T4).
static __device__ __forceinline__ void lgkm_barrier() {
    asm volatile("s_waitcnt lgkmcnt(0)" ::: "memory");
    __builtin_amdgcn_s_barrier();
}

// ---------------------------------------------------------------------------
// Kernel 1: partial Gram G[de][e] over an n-chunk + per-channel sums.
// 512 thr / 8 waves, 1 block/CU (launch_bounds(512,2) -> 256 unified regs/wave).
// Register budget: acc[4][8]=128 AGPR + staging 32 + frags 48 + misc ~30 < 256.
// LOAD-ROLE SPLIT: t<256 loads q, t>=256 loads k (8 f32x4/thread/stage).
// Stage = 32 rows; A/B half pipeline keeps 8 loads/thread outstanding across
// both lgkm-barriers (vmcnt never drains in the main loop).
// LDS [ch][32n] bf16, 16B-slot swizzle slot^((ch>>1)&3) (~2-way conflicts).
// ---------------------------------------------------------------------------
__global__ __launch_bounds__(512, 2)
void k_gram(const float* __restrict__ q, const float* __restrict__ k,
            unsigned short* __restrict__ Gpart, float* __restrict__ Spart, int nchunk)
{
    __shared__ __align__(16) unsigned short ls[2 * DHEAD * 32];   // 32 KB
    unsigned short* lq = ls;
    unsigned short* lk = ls + DHEAD * 32;

    const int t     = threadIdx.x;
    const int bh    = blockIdx.x & 7;
    const int chunk = blockIdx.x >> 3;
    const int b     = bh >> 2, h = bh & 3;
    const int rows  = NTOK / nchunk;    // 512 at nchunk=32
    const int S     = rows >> 5;        // stages of 32 rows
    const int n0c   = chunk * rows;

    const int lane = t & 63, w = t >> 6;
    const int isK  = t >> 8;            // 0: load q, 1: load k
    const int tl   = t & 255;
    const int ng   = tl & 3;            // 4 n-slots of 8 rows
    const int ch0  = (tl >> 2) * 4;     // 64 channel quads
    const int de0  = (w >> 1) * 64;     // 4 row groups
    const int e0   = (w & 1) * 128;     // 2 col groups

    const float* src    = isK ? k : q;
    unsigned short* dst = isK ? lk : lq;
    const float* row0 = src + ((size_t)b * NTOK + n0c + ng * 8) * CDIM + (size_t)h * DHEAD + ch0;

    f32x4 vA[4], vB[4];
#define GL_A(sidx) do { const size_t o_ = (size_t)(sidx) * 32 * CDIM;                \
        _Pragma("unroll") for (int j_ = 0; j_ < 4; ++j_)                              \
            vA[j_] = *reinterpret_cast<const f32x4*>(row0 + o_ + (size_t)j_ * CDIM);   \
        asm volatile("" ::: "memory"); } while (0)
#define GL_B(sidx) do { const size_t o_ = (size_t)(sidx) * 32 * CDIM + 4 * CDIM;     \
        _Pragma("unroll") for (int j_ = 0; j_ < 4; ++j_)                              \
            vB[j_] = *reinterpret_cast<const f32x4*>(row0 + o_ + (size_t)j_ * CDIM);   \
        asm volatile("" ::: "memory"); } while (0)

    GL_A(0);
    GL_B(0);

    float ssum[4] = {0.f, 0.f, 0.f, 0.f};
    f32x4 acc[4][8];
#pragma unroll
    for (int r = 0; r < 4; ++r)
#pragma unroll
        for (int c = 0; c < 8; ++c) acc[r][c] = (f32x4){0.f, 0.f, 0.f, 0.f};

    for (int s = 0; s < S; ++s) {
        // ---- consume half A (rows ng*8+0..3): lower 8B of the 16B slot ----
#pragma unroll
        for (int c = 0; c < 4; ++c) {
            const int ch = ch0 + c;
            ushort4 p;
            p.x = f2bf(vA[0][c]); p.y = f2bf(vA[1][c]);
            p.z = f2bf(vA[2][c]); p.w = f2bf(vA[3][c]);
            ssum[c] += (vA[0][c] + vA[1][c]) + (vA[2][c] + vA[3][c]);
            *reinterpret_cast<ushort4*>(&dst[ch * 32 + ((ng ^ ((ch >> 1) & 3)) * 8)]) = p;
        }
        if (s + 1 < S) GL_A(s + 1);

        // ---- consume half B (rows ng*8+4..7): upper 8B of the slot ----
#pragma unroll
        for (int c = 0; c < 4; ++c) {
            const int ch = ch0 + c;
            ushort4 p;
            p.x = f2bf(vB[0][c]); p.y = f2bf(vB[1][c]);
            p.z = f2bf(vB[2][c]); p.w = f2bf(vB[3][c]);
            ssum[c] += (vB[0][c] + vB[1][c]) + (vB[2][c] + vB[3][c]);
            *reinterpret_cast<ushort4*>(&dst[ch * 32 + ((ng ^ ((ch >> 1) & 3)) * 8) + 4]) = p;
        }
        if (s + 1 < S) GL_B(s + 1);

        lgkm_barrier();

        // ---- MFMA: one K=32 step over the 32 staged rows ----
        {
            s16x8 af[4], bfr[8];
            const int slot = lane >> 4;
#pragma unroll
            for (int r = 0; r < 4; ++r) {
                const int row = de0 + r * 16 + (lane & 15);
                af[r] = *reinterpret_cast<const s16x8*>(&lq[row * 32 + ((slot ^ ((row >> 1) & 3)) * 8)]);
            }
#pragma unroll
            for (int c = 0; c < 8; ++c) {
                const int row = e0 + c * 16 + (lane & 15);
                bfr[c] = *reinterpret_cast<const s16x8*>(&lk[row * 32 + ((slot ^ ((row >> 1) & 3)) * 8)]);
            }
#pragma unroll
            for (int r = 0; r < 4; ++r)
#pragma unroll
                for (int c = 0; c < 8; ++c)
                    acc[r][c] = __builtin_amdgcn_mfma_f32_16x16x32_bf16(af[r], bfr[c], acc[r][c], 0, 0, 0);
        }
        lgkm_barrier();
    }
#undef GL_A
#undef GL_B

    // ---- per-channel partial sums: reduce across the 4-lane ng group ----
#pragma unroll
    for (int off = 1; off < 4; off <<= 1)
#pragma unroll
        for (int c = 0; c < 4; ++c) ssum[c] += __shfl_xor(ssum[c], off);
    if ((lane & 3) == 0) {
        float* sp = Spart + (size_t)(bh * nchunk + chunk) * 512 + isK * 256;
        *reinterpret_cast<float4*>(&sp[ch0]) = make_float4(ssum[0], ssum[1], ssum[2], ssum[3]);
    }

    // ---- Gpart (fp16) via LDS transpose: 4 quarters of 64 de-rows ----
    unsigned short* gp = Gpart + (size_t)(bh * nchunk + chunk) * 65536;
#pragma unroll
    for (int qtr = 0; qtr < 4; ++qtr) {
        if ((w >> 1) == qtr) {
#pragma unroll
            for (int r = 0; r < 4; ++r) {
                const int de_l = r * 16 + (lane >> 4) * 4;
#pragma unroll
                for (int c = 0; c < 8; ++c) {
                    const int e = e0 + c * 16 + (lane & 15);
#pragma unroll
                    for (int reg = 0; reg < 4; ++reg)
                        ls[(de_l + reg) * 256 + e] = f2h(acc[r][c][reg]);
                }
            }
        }
        lgkm_barrier();
#pragma unroll
        for (int i = 0; i < 4; ++i) {
            const int idx = i * 512 + t;
            *reinterpret_cast<u16x8*>(gp + qtr * 16384 + idx * 8) =
                *reinterpret_cast<const u16x8*>(&ls[idx * 8]);
        }
        lgkm_barrier();
    }
}

// ---------------------------------------------------------------------------
// Kernel 2: fused chunk-reduce + scores + softmax (both branches) + W/beta.
// ---------------------------------------------------------------------------
__global__ __launch_bounds__(256)
void k_scores(const unsigned short* __restrict__ Gpart, const float* __restrict__ Spart,
              const float* __restrict__ wqg, const float* __restrict__ bqg,
              const float* __restrict__ wkg, const float* __restrict__ bkg,
              const float* __restrict__ wvg, const float* __restrict__ bvg,
              const float* __restrict__ wql, const float* __restrict__ bql,
              const float* __restrict__ wkl, const float* __restrict__ bkl,
              const float* __restrict__ wvl, const float* __restrict__ bvl,
              const float* __restrict__ wp,  const float* __restrict__ bp,
              unsigned short* __restrict__ Wm, float* __restrict__ beta, int nchunk)
{
    __shared__ float sSq[256], sSk[256];
    const int t  = threadIdx.x;
    const int bh = blockIdx.x >> 5;
    const int rg = blockIdx.x & 31;
    const int h  = bh & 3;

    float aq = 0.f, ak = 0.f;
    for (int c = 0; c < nchunk; ++c) {
        const float* sp = Spart + (size_t)(bh * nchunk + c) * 512;
        aq += sp[t]; ak += sp[256 + t];
    }
    sSq[t] = aq; sSk[t] = ak;
    __syncthreads();

    const int dl  = t >> 5;
    const int de  = rg * 8 + dl;
    const int e8  = (t & 31) * 8;
    const int cd  = h * DHEAD + de;
    const int ce0 = h * DHEAD + e8;

    float g[8] = {0.f, 0.f, 0.f, 0.f, 0.f, 0.f, 0.f, 0.f};
    const unsigned short* gpb = Gpart + (size_t)bh * nchunk * 65536 + (size_t)de * 256 + e8;
    for (int c = 0; c < nchunk; ++c) {
        h16x8 v = *reinterpret_cast<const h16x8*>(gpb + (size_t)c * 65536);
#pragma unroll
        for (int j = 0; j < 8; ++j) g[j] += (float)v[j];
    }

    const float sqv = sSq[de];
    float skv[8];
#pragma unroll
    for (int j = 0; j < 8; ++j) skv[j] = sSk[e8 + j];

    float wrow[8] = {0.f, 0.f, 0.f, 0.f, 0.f, 0.f, 0.f, 0.f};
    float bacc = 0.f;
    const float scale = 0.03125f;
#pragma unroll
    for (int br = 0; br < 2; ++br) {
        const float* wq = br ? wql : wqg;  const float* bq = br ? bql : bqg;
        const float* wk = br ? wkl : wkg;  const float* bk = br ? bkl : bkg;
        const float* wv = br ? wvl : wvg;  const float* bv = br ? bvl : bvg;
        const float wqv = wq[cd], bqv = bq[cd];

        float s[8], m = -1e30f;
#pragma unroll
        for (int j = 0; j < 8; ++j) {
            const float wkv = wk[ce0 + j], bkv = bk[ce0 + j];
            s[j] = scale * (wqv * wkv * g[j] + wqv * bkv * sqv
                            + bqv * wkv * skv[j] + bqv * bkv * 16384.0f);
            m = fmaxf(m, s[j]);
        }
#pragma unroll
        for (int off = 16; off; off >>= 1) m = fmaxf(m, __shfl_xor(m, off));
        float p[8], sum = 0.f;
#pragma unroll
        for (int j = 0; j < 8; ++j) { p[j] = __expf(s[j] - m); sum += p[j]; }
#pragma unroll
        for (int off = 16; off; off >>= 1) sum += __shfl_xor(sum, off);
        const float inv = 1.f / sum;
#pragma unroll
        for (int j = 0; j < 8; ++j) {
            const float a = p[j] * inv;
            wrow[j] += a * wv[ce0 + j];
            bacc    += a * bv[ce0 + j];
        }
    }
    const float wp2 = 2.f * wp[cd];
    u16x8 pw;
#pragma unroll
    for (int j = 0; j < 8; ++j) pw[j] = f2bf(wp2 * wrow[j]);
    *reinterpret_cast<u16x8*>(Wm + (size_t)bh * 65536 + (size_t)de * 256 + e8) = pw;
#pragma unroll
    for (int off = 16; off; off >>= 1) bacc += __shfl_xor(bacc, off);
    if ((t & 31) == 0) beta[bh * 256 + de] = wp2 * bacc + bp[cd];
}

// ---------------------------------------------------------------------------
// Kernel 3: Out[n][dd] = sum_e W[dd][e]*v[n][ce] + beta[dd].
// 256 thr / 4 waves, 64-row tiles, launch_bounds(256,3) -> 3 blocks/CU
// (12 waves/CU) so loads of one block overlap compute/stores of others.
// ---------------------------------------------------------------------------
__global__ __launch_bounds__(256, 3)
void k_out(const float* __restrict__ v, const unsigned short* __restrict__ Wm,
           const float* __restrict__ beta, float* __restrict__ out)
{
    __shared__ __align__(16) unsigned short lv[64 * 256];   // 32 KB
    const int t    = threadIdx.x;
    const int bh   = blockIdx.x & 7;
    const int tile = blockIdx.x >> 3;
    const int b    = bh >> 2, h = bh & 3;
    const int n0   = tile * 64;

#pragma unroll
    for (int i = 0; i < 8; ++i) {
        const int sf = i * 256 + t;
        const int n  = sf >> 5, s = sf & 31;
        const float* vp = v + ((size_t)b * NTOK + n0 + n) * CDIM + (size_t)h * DHEAD + s * 8;
        const float4 v0 = *reinterpret_cast<const float4*>(vp);
        const float4 v1 = *reinterpret_cast<const float4*>(vp + 4);
        const int idx = n * 256 + ((s ^ (n & 7)) * 8);
        *reinterpret_cast<ushort4*>(&lv[idx])     = make_ushort4(f2bf(v0.x), f2bf(v0.y), f2bf(v0.z), f2bf(v0.w));
        *reinterpret_cast<ushort4*>(&lv[idx + 4]) = make_ushort4(f2bf(v1.x), f2bf(v1.y), f2bf(v1.z), f2bf(v1.w));
    }
    __syncthreads();

    const int w = t >> 6, lane = t & 63;
    const int nw  = (w >> 1) * 32;     // 2 n-groups of 32
    const int dd0 = (w & 1) * 128;     // 2 dd-groups of 128
    const unsigned short* Wg = Wm + (size_t)bh * 65536;

    f32x4 acc[2][8];
#pragma unroll
    for (int r = 0; r < 2; ++r)
#pragma unroll
        for (int c = 0; c < 8; ++c) acc[r][c] = (f32x4){0.f, 0.f, 0.f, 0.f};

#pragma unroll
    for (int ks = 0; ks < 8; ++ks) {
        const int e0 = ks * 32;
        s16x8 af[2], bfr[8];
#pragma unroll
        for (int r = 0; r < 2; ++r) {
            const int n  = nw + r * 16 + (lane & 15);
            const int sg = (e0 >> 3) + (lane >> 4);
            af[r] = *reinterpret_cast<const s16x8*>(&lv[n * 256 + ((sg ^ (n & 7)) * 8)]);
        }
#pragma unroll
        for (int c = 0; c < 8; ++c) {
            const int dd = dd0 + c * 16 + (lane & 15);
            const int e  = e0 + (lane >> 4) * 8;
            bfr[c] = *reinterpret_cast<const s16x8*>(Wg + (size_t)dd * 256 + e);
        }
#pragma unroll
        for (int r = 0; r < 2; ++r)
#pragma unroll
            for (int c = 0; c < 8; ++c)
                acc[r][c] = __builtin_amdgcn_mfma_f32_16x16x32_bf16(af[r], bfr[c], acc[r][c], 0, 0, 0);
    }

    float betar[8];
#pragma unroll
    for (int c = 0; c < 8; ++c) betar[c] = beta[bh * 256 + dd0 + c * 16 + (lane & 15)];

#pragma unroll
    for (int r = 0; r < 2; ++r)
#pragma unroll
        for (int c = 0; c < 8; ++c) {
            const int dd = dd0 + c * 16 + (lane & 15);
#pragma unroll
            for (int reg = 0; reg < 4; ++reg) {
                const int n = nw + r * 16 + (lane >> 4) * 4 + reg;
                out[((size_t)b * NTOK + n0 + n) * CDIM + (size_t)h * DHEAD + dd] =
                    acc[r][c][reg] + betar[c];
            }
        }
}

// ---------------------------------------------------------------------------
extern "C" void kernel_launch(void* const* d_in, const int* in_sizes, int n_in,
                              void* d_out, int out_size, void* d_ws, size_t ws_size,
                              hipStream_t stream)
{
    const float* q = (const float*)d_in[0];
    const float* k = (const float*)d_in[1];
    const float* v = (const float*)d_in[2];
    const float* wgt[14];
    for (int i = 0; i < 14; ++i) wgt[i] = (const float*)d_in[3 + i];
    float* out = (float*)d_out;

    int nchunk = 32;
    while (nchunk > 1) {
        size_t need = (size_t)8 * nchunk * 65536 * 2   // Gpart fp16
                    + (size_t)8 * nchunk * 512 * 4     // Spart
                    + (size_t)8 * 65536 * 2            // W bf16
                    + (size_t)8 * 256 * 4 + 1024;      // beta + slack
        if (need <= ws_size) break;
        nchunk >>= 1;
    }

    char* p = (char*)d_ws;
    unsigned short* Gpart = (unsigned short*)p; p += (size_t)8 * nchunk * 65536 * 2;
    float* Spart = (float*)p;                   p += (size_t)8 * nchunk * 512 * 4;
    unsigned short* Wm = (unsigned short*)p;    p += (size_t)8 * 65536 * 2;
    float* beta  = (float*)p;

    k_gram<<<dim3(8 * nchunk), dim3(512), 0, stream>>>(q, k, Gpart, Spart, nchunk);
    k_scores<<<dim3(8 * 32), dim3(256), 0, stream>>>(
        Gpart, Spart,
        wgt[0], wgt[1], wgt[2], wgt[3], wgt[4], wgt[5],
        wgt[6], wgt[7], wgt[8], wgt[9], wgt[10], wgt[11],
        wgt[12], wgt[13], Wm, beta, nchunk);
    k_out<<<dim3(8 * 256), dim3(256), 0, stream>>>(v, Wm, beta, out);
}